// Round 2
// baseline (224.809 us; speedup 1.0000x reference)
//
#include <hip/hip_runtime.h>

// LIF scan, T=8, N=4M fp32. 256 MiB logical traffic; fills in this trace hit
// 6.5-6.7 TB/s, copy ~6.3 -> ~43 us ideal kernel. Ladder: R1-R4 capped 2.2 TB/s
// by cache-allocate reads -> NT loads (R5, ~78 us, 3.4 TB/s). R5==R6==R8==R9:
// burst depth, pipeline, store policy, TLB chunking all neutral.
// R10 theory: per-wave 16-stream interleave (8 ld + 8 st, 16 MiB apart) is the
// residual difference vs the 6.3 TB/s copy pattern (1-2 sequential streams per
// wave). Fix: wave<->timestep mapping. Wave w DMAs its contiguous slab of
// stream t=w to LDS (global_load_lds x4, NT), threads scan columns in LDS
// (spikes overwrite x in place), wave w streams out[t=w] back. Every wave's
// global traffic is now a single sequential stream. Double-buffered with raw
// s_barrier + counted vmcnt (never 0 in loop) so tile k+1 DMA hides under
// tile k compute+store. 2x32KB LDS, ~40 VGPR -> 2 blocks/CU, 16 waves/CU.
// R11: R10 never ran (container infra failure, no counters). Re-submit with
// hardened barriers: asm s_barrier with "memory" clobber so no ds_read can be
// hoisted across a barrier by alias analysis (m152-class race; the intrinsic
// s_barrier is not a compiler memory fence).

#define LIF_THRESH 0.5f
#define LIF_BETA   0.25f
#define LIF_T      8
#define BLOCK      512            // 8 waves; wave w <-> time-stream t=w
#define TILE_W     256            // v4f columns per tile (32 KiB x-slab)
#define TILES      8              // tiles per block -> block owns 2048 v4f cols

typedef float v4f __attribute__((ext_vector_type(4)));
typedef float v2f __attribute__((ext_vector_type(2)));

template <int N>
__device__ __forceinline__ void wait_vmcnt() {
    asm volatile("s_waitcnt vmcnt(%0)" ::"n"(N) : "memory");
}
__device__ __forceinline__ void wait_lgkmcnt0() {
    asm volatile("s_waitcnt lgkmcnt(0)" ::: "memory");
}
__device__ __forceinline__ void barrier_fenced() {
    // s_barrier that is ALSO a compiler memory fence: no LDS op may be
    // scheduled across it (the builtin alone is not a memory barrier).
    asm volatile("s_barrier" ::: "memory");
}

__global__ __launch_bounds__(BLOCK) void lif_kernel(const v4f* __restrict__ x,
                                                    v4f* __restrict__ out,
                                                    int n4) {
    __shared__ v4f xs[2][LIF_T][TILE_W];   // 2 x 32 KiB double buffer

    const int wave = threadIdx.x >> 6;
    const int lane = threadIdx.x & 63;
    const size_t col0  = (size_t)blockIdx.x * (TILE_W * TILES);
    const size_t gbase = (size_t)wave * (size_t)n4 + col0;   // stream t = wave

    // Stage one tile into buf: per wave, 4x global_load_lds_dwordx4 (nt).
    // LDS dst is wave-uniform base + lane*16 (linear, m104 constraint OK);
    // global src is per-lane sequential within the wave's single stream.
#define STAGE(tile, buf)                                                       \
    {                                                                          \
        _Pragma("unroll")                                                      \
        for (int i = 0; i < TILE_W / 64; ++i) {                                \
            __builtin_amdgcn_global_load_lds(                                  \
                (const __attribute__((address_space(1))) void*)                \
                    (&x[gbase + (size_t)(tile)*TILE_W + i * 64 + lane]),       \
                (__attribute__((address_space(3))) void*)                      \
                    (&xs[buf][wave][i * 64]),                                  \
                16, 0, 2 /* nt: read-once streaming, the R5 win */);           \
        }                                                                      \
    }

    STAGE(0, 0);

#pragma unroll
    for (int k = 0; k < TILES; ++k) {
        const int buf = k & 1;

        // Prefetch tile k+1 into the other buffer before consuming tile k.
        // Safe vs iter k-1: this wave's DMA touches only its OWN row of
        // buf^1, whose store ds_reads drained (data dep) before the stores
        // that precede this point in program order.
        if (k + 1 < TILES) STAGE(k + 1, buf ^ 1);

        // Wait for OWN tile-k loads only. VMEM newer than them (in-order
        // retirement): 4 prefetch loads (if issued) + 4 NT stores from iter
        // k-1 (if any).
        if (k == 0)             wait_vmcnt<4>();
        else if (k + 1 < TILES) wait_vmcnt<8>();
        else                    wait_vmcnt<4>();
        barrier_fenced();   // all 8 waves' slabs of tile k now resident

        // Compute: thread ci owns float2-column ci; full t-scan in LDS.
        // Spikes overwrite x in place (same thread, same address, rd->wr).
        {
            const int ci = threadIdx.x;
            float m0 = 0.f, m1 = 0.f;
#pragma unroll
            for (int t = 0; t < LIF_T; ++t) {
                v2f xv = ((const v2f*)xs[buf][t])[ci];
                m0 = m0 * LIF_BETA + xv.x;
                m1 = m1 * LIF_BETA + xv.y;
                v2f s;
                s.x = (m0 >= LIF_THRESH) ? 1.f : 0.f;
                s.y = (m1 >= LIF_THRESH) ? 1.f : 0.f;
                m0 = (m0 >= LIF_THRESH) ? 0.f : m0;
                m1 = (m1 >= LIF_THRESH) ? 0.f : m1;
                ((v2f*)xs[buf][t])[ci] = s;
            }
        }

        // Spikes in row t were written by threads of ALL waves -> drain own
        // ds_writes, then barrier, before cross-wave store reads.
        wait_lgkmcnt0();
        __builtin_amdgcn_sched_barrier(0);   // rule-18 insurance
        barrier_fenced();

        // Store: wave w streams spikes of out[t=w] -- one sequential stream.
#pragma unroll
        for (int i = 0; i < TILE_W / 64; ++i) {
            v4f s = xs[buf][wave][i * 64 + lane];
            __builtin_nontemporal_store(
                s, &out[gbase + (size_t)k * TILE_W + i * 64 + lane]);
        }
        // No barrier here: next iter's DMA into buf^1 only touches the
        // issuing wave's own row, and its own store ds_reads completed
        // before those stores issued (data dependency).
    }
#undef STAGE
}

extern "C" void kernel_launch(void* const* d_in, const int* in_sizes, int n_in,
                              void* d_out, int out_size, void* d_ws, size_t ws_size,
                              hipStream_t stream) {
    const v4f* x = (const v4f*)d_in[0];
    v4f* out = (v4f*)d_out;

    long long total = in_sizes[0];
    int n = (int)(total / LIF_T);   // 4,194,304 floats per timestep
    int n4 = n / 4;                 // 1,048,576 v4f columns per timestep

    dim3 block(BLOCK);
    dim3 grid(n4 / (TILE_W * TILES));   // 512 blocks -> 2/CU, 16 waves/CU
    lif_kernel<<<grid, block, 0, stream>>>(x, out, n4);
}